// Round 17
// baseline (1863.411 us; speedup 1.0000x reference)
//
#include <hip/hip_runtime.h>
#include <cmath>

// Problem constants
static constexpr int NB   = 128;   // batch
static constexpr int NT   = 512;   // time
static constexpr int ND   = 128;   // embed dim
static constexpr int NH   = 128;   // hidden per direction
static constexpr int NG4  = 512;   // 4*H
static constexpr int NKT  = 32;    // num tags
static constexpr int CHUNK = 128;  // timesteps per chunk
static constexpr int NCH  = NT / CHUNK;

__device__ __forceinline__ float sigf(float x) { return 1.0f / (1.0f + expf(-x)); }

// ---------------------------------------------------------------------------
// Weight pre-pack: wt[((d*2+ct)*KT + kt)*4096 + k*256 + j] = W[(d*512+ct*256+j)*DIN + kt*16+k]
// ---------------------------------------------------------------------------
__global__ __launch_bounds__(256) void prep_w(
    const float* __restrict__ W, float* __restrict__ wt, int DIN)
{
    const int KT = DIN >> 4;
    const int o = blockIdx.x * 256 + threadIdx.x;   // < 2*512*DIN
    const int j  = o & 255;
    const int k  = (o >> 8) & 15;
    const int cb = o >> 12;          // (d*2+ct)*KT + kt
    const int kt = cb % KT;
    const int dct = cb / KT;
    const int d  = dct >> 1;
    const int ct = dct & 1;
    wt[o] = W[(size_t)(d * 512 + ct * 256 + j) * DIN + kt * 16 + k];
}

// ---------------------------------------------------------------------------
// Projection GEMM (proven v4, ~54us/dispatch): 256 threads, tile 128x256,
// thread tile 16x8, packed-weight coalesced B staging.
// ---------------------------------------------------------------------------
template <int DIN>
__device__ __forceinline__ void proj_body(
    const float* __restrict__ wt,     // packed [d][ct][kt][16][256]
    const float* __restrict__ bias,   // [2][512]
    const float* __restrict__ xsrc,   // emb [V][128] (l0) or h1 [B][T][256] (l1)
    const int*   __restrict__ inputs, // [B][T] (l0 only)
    float*       __restrict__ zin,    // [2][B][CHUNK][512]
    int c)
{
    constexpr int KT = DIN / 16;
    __shared__ __align__(16) float A[2][16][128];
    __shared__ __align__(16) float Bs[2][16][256];
    __shared__ const float* rowp[128];

    const int bid = blockIdx.x;
    const int d  = bid >> 8;
    const int b  = (bid >> 1) & 127;
    const int ct = bid & 1;
    const int tid = threadIdx.x;
    const int tx = tid & 31;    // cols: ct*256 + {tx*4..+3, 128+tx*4..+3}
    const int ty = tid >> 5;    // rows: ty*16 .. ty*16+15
    const int q  = tid & 3;     // A staging k-quad: k = q*4..q*4+3
    const int r0 = tid >> 2;    // A staging rows r0 and r0+64

    if (tid < 128) {
        const int s = tid;
        const int ttl = c * CHUNK + s;
        const int t = d ? (NT - 1 - ttl) : ttl;
        if constexpr (DIN == 128) {
            rowp[tid] = xsrc + (size_t)inputs[b * NT + t] * ND;
        } else {
            rowp[tid] = xsrc + ((size_t)(b * NT + t)) * 256;
        }
    }
    __syncthreads();

    const float* rp0 = rowp[r0];
    const float* rp1 = rowp[r0 + 64];
    const float* wtb = wt + ((size_t)(d * 2 + ct)) * KT * 4096;

    float acc[16][8];
#pragma unroll
    for (int i = 0; i < 16; ++i)
#pragma unroll
        for (int n = 0; n < 8; ++n) acc[i][n] = 0.0f;

    // Prefetch kt=0.
    float4 pa0 = *(const float4*)(rp0 + q * 4);
    float4 pa1 = *(const float4*)(rp1 + q * 4);
    float4 pb0 = ((const float4*)wtb)[tid];
    float4 pb1 = ((const float4*)wtb)[tid + 256];
    float4 pb2 = ((const float4*)wtb)[tid + 512];
    float4 pb3 = ((const float4*)wtb)[tid + 768];

    for (int kt = 0; kt < KT; ++kt) {
        const int buf = kt & 1;
        // Stage A: A[q*4+kk][r]
        A[buf][q * 4 + 0][r0] = pa0.x; A[buf][q * 4 + 1][r0] = pa0.y;
        A[buf][q * 4 + 2][r0] = pa0.z; A[buf][q * 4 + 3][r0] = pa0.w;
        A[buf][q * 4 + 0][r0 + 64] = pa1.x; A[buf][q * 4 + 1][r0 + 64] = pa1.y;
        A[buf][q * 4 + 2][r0 + 64] = pa1.z; A[buf][q * 4 + 3][r0 + 64] = pa1.w;
        // Stage B: packed float4 e -> Bs[e>>6][(e&63)*4]
        {
            const int e0 = tid;        *(float4*)&Bs[buf][e0 >> 6][(e0 & 63) * 4] = pb0;
            const int e1 = tid + 256;  *(float4*)&Bs[buf][e1 >> 6][(e1 & 63) * 4] = pb1;
            const int e2 = tid + 512;  *(float4*)&Bs[buf][e2 >> 6][(e2 & 63) * 4] = pb2;
            const int e3 = tid + 768;  *(float4*)&Bs[buf][e3 >> 6][(e3 & 63) * 4] = pb3;
        }
        __syncthreads();

        if (kt + 1 < KT) {
            const int k0 = (kt + 1) * 16;
            pa0 = *(const float4*)(rp0 + k0 + q * 4);
            pa1 = *(const float4*)(rp1 + k0 + q * 4);
            const float4* wkt = (const float4*)(wtb + (size_t)(kt + 1) * 4096);
            pb0 = wkt[tid];
            pb1 = wkt[tid + 256];
            pb2 = wkt[tid + 512];
            pb3 = wkt[tid + 768];
        }

#pragma unroll 2
        for (int k = 0; k < 16; ++k) {
            float4 a0 = *(const float4*)&A[buf][k][ty * 16];
            float4 a1 = *(const float4*)&A[buf][k][ty * 16 + 4];
            float4 a2 = *(const float4*)&A[buf][k][ty * 16 + 8];
            float4 a3 = *(const float4*)&A[buf][k][ty * 16 + 12];
            float4 b0 = *(const float4*)&Bs[buf][k][tx * 4];
            float4 b1 = *(const float4*)&Bs[buf][k][128 + tx * 4];
            const float ar[16] = {a0.x, a0.y, a0.z, a0.w, a1.x, a1.y, a1.z, a1.w,
                                  a2.x, a2.y, a2.z, a2.w, a3.x, a3.y, a3.z, a3.w};
            const float br[8]  = {b0.x, b0.y, b0.z, b0.w, b1.x, b1.y, b1.z, b1.w};
#pragma unroll
            for (int i = 0; i < 16; ++i)
#pragma unroll
                for (int n = 0; n < 8; ++n) acc[i][n] += ar[i] * br[n];
        }
    }

    float4 bb0 = *(const float4*)(bias + d * NG4 + ct * 256 + tx * 4);
    float4 bb1 = *(const float4*)(bias + d * NG4 + ct * 256 + 128 + tx * 4);
#pragma unroll
    for (int i = 0; i < 16; ++i) {
        const int s = ty * 16 + i;
        float* zp = zin + (((size_t)(d * NB + b) * CHUNK + s)) * NG4 + ct * 256;
        float4 o0, o1;
        o0.x = acc[i][0] + bb0.x; o0.y = acc[i][1] + bb0.y;
        o0.z = acc[i][2] + bb0.z; o0.w = acc[i][3] + bb0.w;
        o1.x = acc[i][4] + bb1.x; o1.y = acc[i][5] + bb1.y;
        o1.z = acc[i][6] + bb1.z; o1.w = acc[i][7] + bb1.w;
        *(float4*)(zp + tx * 4) = o0;
        *(float4*)(zp + 128 + tx * 4) = o1;
    }
}

__global__ __launch_bounds__(256) void proj_l0(
    const float* __restrict__ wt, const float* __restrict__ bias,
    const float* __restrict__ xsrc, const int* __restrict__ inputs,
    float* __restrict__ zin, int c)
{ proj_body<128>(wt, bias, xsrc, inputs, zin, c); }

__global__ __launch_bounds__(256) void proj_l1(
    const float* __restrict__ wt, const float* __restrict__ bias,
    const float* __restrict__ xsrc, const int* __restrict__ inputs,
    float* __restrict__ zin, int c)
{ proj_body<256>(wt, bias, xsrc, inputs, zin, c); }

// ---------------------------------------------------------------------------
// Recurrent kernel (R16's ks8, ~140us/dispatch — unchanged).
// ---------------------------------------------------------------------------
__global__ __launch_bounds__(512, 2) void lstm_rec_ks8(
    const float* __restrict__ Whh,     // [2][512][128]
    const float* __restrict__ zin,     // [2][B][CHUNK][512]
    float*       __restrict__ hout,    // [B][T][256]; slice [d*128, d*128+128)
    float*       __restrict__ state_h, // [2][B][128]
    float*       __restrict__ state_c, // [2][B][128]
    int c)
{
    __shared__ __align__(16) float h_lds[128];
    __shared__ __align__(16) float p_lds[4][512];   // [k-quarter][row]

    const int bid = blockIdx.x;  // d*128 + b
    const int d = bid >> 7, b = bid & 127;
    const int tid = threadIdx.x;
    const int wave = tid >> 6;
    const int g  = wave >> 2;    // row-half: rows [256g, 256g+256)
    const int wv = wave & 3;     // k-quarter: k in [32wv, 32wv+32)
    const int l  = tid & 63;

    // Weights: rows 256g + l + 64i (i=0..3), k in [32wv, 32wv+32).
    float w[4][32];
#pragma unroll
    for (int i = 0; i < 4; ++i) {
        const float* wr = Whh + ((size_t)(d * NG4 + 256 * g + l + 64 * i)) * NH + wv * 32;
#pragma unroll
        for (int kk = 0; kk < 32; kk += 4) {
            float4 t4 = *(const float4*)(wr + kk);
            w[i][kk] = t4.x; w[i][kk + 1] = t4.y; w[i][kk + 2] = t4.z; w[i][kk + 3] = t4.w;
        }
    }

    float c_reg = 0.0f;
    if (tid < 128) {
        float h0 = 0.0f;
        if (c != 0) {
            h0    = state_h[(d * NB + b) * NH + tid];
            c_reg = state_c[(d * NB + b) * NH + tid];
        }
        h_lds[tid] = h0;
    }
    __syncthreads();

    const float* zb = zin + ((size_t)(d * NB + b)) * CHUNK * NG4;

    for (int s = 0; s < CHUNK; ++s) {
        // gate lanes prefetch this step's zin early (in flight under FMA)
        float z0 = 0.f, z1 = 0.f, z2 = 0.f, z3 = 0.f;
        if (tid < 128) {
            const float* zr = zb + (size_t)s * NG4;
            z0 = zr[tid]; z1 = zr[128 + tid]; z2 = zr[256 + tid]; z3 = zr[384 + tid];
        }

        // FMA phase: read the wave's 32-float h segment (8 broadcast b128)
        float hv[32];
        const float* hp = h_lds + wv * 32;
#pragma unroll
        for (int kk = 0; kk < 32; kk += 4) {
            float4 t4 = *(const float4*)(hp + kk);
            hv[kk] = t4.x; hv[kk + 1] = t4.y; hv[kk + 2] = t4.z; hv[kk + 3] = t4.w;
        }
#pragma unroll
        for (int i = 0; i < 4; ++i) {
            float a = 0.0f;
#pragma unroll
            for (int kk = 0; kk < 32; ++kk) a += w[i][kk] * hv[kk];
            p_lds[wv][256 * g + l + 64 * i] = a;   // lanes consecutive: conflict-free
        }
        __syncthreads();

        if (tid < 128) {
            const float si = (p_lds[0][tid] + p_lds[1][tid]) + (p_lds[2][tid] + p_lds[3][tid]);
            const float sf = (p_lds[0][128 + tid] + p_lds[1][128 + tid]) + (p_lds[2][128 + tid] + p_lds[3][128 + tid]);
            const float sg = (p_lds[0][256 + tid] + p_lds[1][256 + tid]) + (p_lds[2][256 + tid] + p_lds[3][256 + tid]);
            const float so = (p_lds[0][384 + tid] + p_lds[1][384 + tid]) + (p_lds[2][384 + tid] + p_lds[3][384 + tid]);
            const float zi = z0 + si;
            const float zf = z1 + sf;
            const float zg = z2 + sg;
            const float zo = z3 + so;
            const float ig = sigf(zi), fg = sigf(zf), og = sigf(zo);
            c_reg = fg * c_reg + ig * tanhf(zg);
            const float hn = og * tanhf(c_reg);
            const int ttl = c * CHUNK + s;
            const int t   = d ? (NT - 1 - ttl) : ttl;
            h_lds[tid] = hn;
            hout[((size_t)(b * NT + t)) * 256 + d * NH + tid] = hn;
        }
        __syncthreads();
    }

    if (tid < 128) {
        state_h[(d * NB + b) * NH + tid] = h_lds[tid];
        state_c[(d * NB + b) * NH + tid] = c_reg;
    }
}

// ---------------------------------------------------------------------------
// Emissions: em[b][t][k] = b_out[k] + sum_c h2[b][t][c] * W_out[k][c]
// ---------------------------------------------------------------------------
__global__ __launch_bounds__(256) void emis_kernel(
    const float* __restrict__ h2,    // [B][T][256]
    const float* __restrict__ Wout,  // [32][256]
    const float* __restrict__ bout,  // [32]
    float*       __restrict__ em)    // [B][T][32]
{
    __shared__ float wt[256 * 32];               // transposed [c][k]
    __shared__ __align__(16) float hrow[8][256];

    const int tid = threadIdx.x;
    const int k = tid & 31;
    const int rl = tid >> 5;  // 0..7

    for (int e = tid; e < 8192; e += 256) {
        const int kk = e >> 8, cc = e & 255;
        wt[cc * 32 + kk] = Wout[e];
    }
    const float bk = bout[k];
    __syncthreads();

    const size_t base = (size_t)blockIdx.x * 64;
    for (int rr = 0; rr < 8; ++rr) {
        const size_t r0 = base + rr * 8;
        for (int e = tid; e < 512; e += 256) {
            ((float4*)&hrow[0][0])[e] = ((const float4*)(h2 + r0 * 256))[e];
        }
        __syncthreads();
        float acc = bk;
#pragma unroll 8
        for (int cc = 0; cc < 256; cc += 4) {
            float4 hv = *(const float4*)&hrow[rl][cc];
            acc += hv.x * wt[cc * 32 + k] + hv.y * wt[(cc + 1) * 32 + k] +
                   hv.z * wt[(cc + 2) * 32 + k] + hv.w * wt[(cc + 3) * 32 + k];
        }
        em[(r0 + rl) * NKT + k] = acc;
        __syncthreads();
    }
}

// ---------------------------------------------------------------------------
// Viterbi v5: barrier-free single-wave scan (R11-proven) + R4/R5-proven fast
// inner step: tr in REGISTERS (no per-step tr LDS reads), score via 4x
// ds_read_b128 broadcast, in-lane argmax TREE (left >= == first-index-wins,
// absmax-0-proven in R4/R5), 1 cross-half shfl. Decision semantics identical.
// ---------------------------------------------------------------------------
__global__ __launch_bounds__(64) void viterbi_tree(
    const float* __restrict__ em,      // [B][T][32]
    const float* __restrict__ start_t, // [32]
    const float* __restrict__ end_t,   // [32]
    const float* __restrict__ trans,   // [32][32]
    int*         __restrict__ out)     // [B][T]
{
    __shared__ __align__(16) float score[32];
    __shared__ float fsc[32];
    __shared__ unsigned char hist[(NT - 1) * 32];

    const int b = blockIdx.x;
    const int lane = threadIdx.x;
    const int j = lane & 31, h = lane >> 5;

    float tr_reg[16];
#pragma unroll
    for (int ii = 0; ii < 16; ++ii) tr_reg[ii] = trans[(h * 16 + ii) * 32 + j];
    const float et = end_t[j];

    const float* emb_ = em + (size_t)b * NT * NKT;
    if (lane < 32) score[j] = start_t[j] + emb_[j];
    __syncthreads();  // once (init ordering; single wave thereafter)

    float em_next = emb_[NKT + j];  // t = 1
    for (int t = 1; t < NT; ++t) {
        const float em_j = em_next;
        if (t + 1 < NT) em_next = emb_[(size_t)(t + 1) * NKT + j];

        // batched broadcast read of the 16 scores this half reduces over
        float4 s0 = *(const float4*)&score[h * 16];
        float4 s1 = *(const float4*)&score[h * 16 + 4];
        float4 s2 = *(const float4*)&score[h * 16 + 8];
        float4 s3 = *(const float4*)&score[h * 16 + 12];
        const float sc[16] = {s0.x, s0.y, s0.z, s0.w, s1.x, s1.y, s1.z, s1.w,
                              s2.x, s2.y, s2.z, s2.w, s3.x, s3.y, s3.z, s3.w};

        float v[16];
#pragma unroll
        for (int ii = 0; ii < 16; ++ii) {
            v[ii] = (sc[ii] + tr_reg[ii]) + em_j;  // np add order
        }
        // in-lane argmax tree, left (lower index) preferred on ties
        float l1v[8]; int l1i[8];
#pragma unroll
        for (int p = 0; p < 8; ++p) {
            const bool L = v[2 * p] >= v[2 * p + 1];
            l1v[p] = L ? v[2 * p] : v[2 * p + 1];
            l1i[p] = L ? 2 * p : 2 * p + 1;
        }
        float l2v[4]; int l2i[4];
#pragma unroll
        for (int p = 0; p < 4; ++p) {
            const bool L = l1v[2 * p] >= l1v[2 * p + 1];
            l2v[p] = L ? l1v[2 * p] : l1v[2 * p + 1];
            l2i[p] = L ? l1i[2 * p] : l1i[2 * p + 1];
        }
        float l3v[2]; int l3i[2];
#pragma unroll
        for (int p = 0; p < 2; ++p) {
            const bool L = l2v[2 * p] >= l2v[2 * p + 1];
            l3v[p] = L ? l2v[2 * p] : l2v[2 * p + 1];
            l3i[p] = L ? l2i[2 * p] : l2i[2 * p + 1];
        }
        const bool L4 = l3v[0] >= l3v[1];
        const float best = L4 ? l3v[0] : l3v[1];
        const int   bi   = h * 16 + (L4 ? l3i[0] : l3i[1]);

        // cross-half combine (ties -> low half -> smaller i)
        const float ob  = __shfl(best, lane ^ 32);
        const int   obi = __shfl(bi,   lane ^ 32);
        const bool take_other = h ? (ob >= best) : (ob > best);
        const float ns = take_other ? ob : best;
        const int  arg = take_other ? obi : bi;

        // no barrier: single-wave lockstep; DS ops in order
        if (h == 0) {
            score[j] = ns;
            hist[(t - 1) * 32 + j] = (unsigned char)arg;
        }
    }

    if (lane < 32) fsc[j] = score[j] + et;
    if (lane == 0) {
        float best = -1e30f; int bi = 0;
        for (int i = 0; i < 32; ++i) {
            const float v = fsc[i];
            if (v > best) { best = v; bi = i; }
        }
        int tag = bi;
        out[b * NT + (NT - 1)] = tag;
        for (int t = NT - 2; t >= 0; --t) {
            tag = hist[t * 32 + tag];
            out[b * NT + t] = tag;
        }
    }
}

// ---------------------------------------------------------------------------
extern "C" void kernel_launch(void* const* d_in, const int* in_sizes, int n_in,
                              void* d_out, int out_size, void* d_ws, size_t ws_size,
                              hipStream_t stream) {
    const int*   inputs  = (const int*)d_in[0];
    // d_in[1] = tags (unused by forward/decode)
    const float* emb     = (const float*)d_in[2];
    const float* w_ih_l0 = (const float*)d_in[3];
    const float* w_hh_l0 = (const float*)d_in[4];
    const float* b_l0    = (const float*)d_in[5];
    const float* w_ih_l1 = (const float*)d_in[6];
    const float* w_hh_l1 = (const float*)d_in[7];
    const float* b_l1    = (const float*)d_in[8];
    const float* W_out   = (const float*)d_in[9];
    const float* b_out   = (const float*)d_in[10];
    const float* start_t = (const float*)d_in[11];
    const float* end_t   = (const float*)d_in[12];
    const float* trans   = (const float*)d_in[13];
    int* out = (int*)d_out;

    float* ws  = (float*)d_ws;
    float* zin = ws;                                        // 2*B*128*512
    float* h1  = zin + (size_t)2 * NB * CHUNK * NG4;        // B*T*256
    float* h2  = h1 + (size_t)NB * NT * 256;                // B*T*256
    float* sth = h2 + (size_t)NB * NT * 256;                // 2*B*128
    float* stc = sth + (size_t)2 * NB * NH;                 // 2*B*128
    float* em  = stc + (size_t)2 * NB * NH;                 // B*T*32
    float* wt0 = em + (size_t)NB * NT * NKT;                // 2*512*128
    float* wt1 = wt0 + (size_t)2 * 512 * 128;               // 2*512*256

    // Pre-pack weights into k-major staging layout (coalesced proj B-loads).
    prep_w<<<512, 256, 0, stream>>>(w_ih_l0, wt0, 128);
    prep_w<<<1024, 256, 0, stream>>>(w_ih_l1, wt1, 256);

    // Layer 0: chunked input-projection GEMM + recurrence
    for (int c = 0; c < NCH; ++c) {
        proj_l0<<<512, 256, 0, stream>>>(wt0, b_l0, emb, inputs, zin, c);
        lstm_rec_ks8<<<256, 512, 0, stream>>>(w_hh_l0, zin, h1, sth, stc, c);
    }
    // Layer 1
    for (int c = 0; c < NCH; ++c) {
        proj_l1<<<512, 256, 0, stream>>>(wt1, b_l1, h1, nullptr, zin, c);
        lstm_rec_ks8<<<256, 512, 0, stream>>>(w_hh_l1, zin, h2, sth, stc, c);
    }
    // Emissions + Viterbi decode
    emis_kernel<<<(NB * NT) / 64, 256, 0, stream>>>(h2, W_out, b_out, em);
    viterbi_tree<<<NB, 64, 0, stream>>>(em, start_t, end_t, trans, out);
}

// Round 18
// 1772.105 us; speedup vs baseline: 1.0515x; 1.0515x over previous
//
#include <hip/hip_runtime.h>
#include <cmath>

// Problem constants
static constexpr int NB   = 128;   // batch
static constexpr int NT   = 512;   // time
static constexpr int ND   = 128;   // embed dim
static constexpr int NH   = 128;   // hidden per direction
static constexpr int NG4  = 512;   // 4*H
static constexpr int NKT  = 32;    // num tags
static constexpr int CHUNK = 128;  // timesteps per chunk
static constexpr int NCH  = NT / CHUNK;

__device__ __forceinline__ float sigf(float x) { return 1.0f / (1.0f + expf(-x)); }

// ---------------------------------------------------------------------------
// Weight pre-pack: wt[((d*2+ct)*KT + kt)*4096 + k*256 + j] = W[(d*512+ct*256+j)*DIN + kt*16+k]
// ---------------------------------------------------------------------------
__global__ __launch_bounds__(256) void prep_w(
    const float* __restrict__ W, float* __restrict__ wt, int DIN)
{
    const int KT = DIN >> 4;
    const int o = blockIdx.x * 256 + threadIdx.x;   // < 2*512*DIN
    const int j  = o & 255;
    const int k  = (o >> 8) & 15;
    const int cb = o >> 12;          // (d*2+ct)*KT + kt
    const int kt = cb % KT;
    const int dct = cb / KT;
    const int d  = dct >> 1;
    const int ct = dct & 1;
    wt[o] = W[(size_t)(d * 512 + ct * 256 + j) * DIN + kt * 16 + k];
}

// ---------------------------------------------------------------------------
// Projection GEMM (proven v4, ~54us/dispatch; ~76% of fp32 VALU roofline):
// 256 threads, tile 128x256, thread tile 16x8, packed-weight staging.
// ---------------------------------------------------------------------------
template <int DIN>
__device__ __forceinline__ void proj_body(
    const float* __restrict__ wt,     // packed [d][ct][kt][16][256]
    const float* __restrict__ bias,   // [2][512]
    const float* __restrict__ xsrc,   // emb [V][128] (l0) or h1 [B][T][256] (l1)
    const int*   __restrict__ inputs, // [B][T] (l0 only)
    float*       __restrict__ zin,    // [2][B][CHUNK][512]
    int c)
{
    constexpr int KT = DIN / 16;
    __shared__ __align__(16) float A[2][16][128];
    __shared__ __align__(16) float Bs[2][16][256];
    __shared__ const float* rowp[128];

    const int bid = blockIdx.x;
    const int d  = bid >> 8;
    const int b  = (bid >> 1) & 127;
    const int ct = bid & 1;
    const int tid = threadIdx.x;
    const int tx = tid & 31;    // cols: ct*256 + {tx*4..+3, 128+tx*4..+3}
    const int ty = tid >> 5;    // rows: ty*16 .. ty*16+15
    const int q  = tid & 3;     // A staging k-quad: k = q*4..q*4+3
    const int r0 = tid >> 2;    // A staging rows r0 and r0+64

    if (tid < 128) {
        const int s = tid;
        const int ttl = c * CHUNK + s;
        const int t = d ? (NT - 1 - ttl) : ttl;
        if constexpr (DIN == 128) {
            rowp[tid] = xsrc + (size_t)inputs[b * NT + t] * ND;
        } else {
            rowp[tid] = xsrc + ((size_t)(b * NT + t)) * 256;
        }
    }
    __syncthreads();

    const float* rp0 = rowp[r0];
    const float* rp1 = rowp[r0 + 64];
    const float* wtb = wt + ((size_t)(d * 2 + ct)) * KT * 4096;

    float acc[16][8];
#pragma unroll
    for (int i = 0; i < 16; ++i)
#pragma unroll
        for (int n = 0; n < 8; ++n) acc[i][n] = 0.0f;

    // Prefetch kt=0.
    float4 pa0 = *(const float4*)(rp0 + q * 4);
    float4 pa1 = *(const float4*)(rp1 + q * 4);
    float4 pb0 = ((const float4*)wtb)[tid];
    float4 pb1 = ((const float4*)wtb)[tid + 256];
    float4 pb2 = ((const float4*)wtb)[tid + 512];
    float4 pb3 = ((const float4*)wtb)[tid + 768];

    for (int kt = 0; kt < KT; ++kt) {
        const int buf = kt & 1;
        // Stage A: A[q*4+kk][r]
        A[buf][q * 4 + 0][r0] = pa0.x; A[buf][q * 4 + 1][r0] = pa0.y;
        A[buf][q * 4 + 2][r0] = pa0.z; A[buf][q * 4 + 3][r0] = pa0.w;
        A[buf][q * 4 + 0][r0 + 64] = pa1.x; A[buf][q * 4 + 1][r0 + 64] = pa1.y;
        A[buf][q * 4 + 2][r0 + 64] = pa1.z; A[buf][q * 4 + 3][r0 + 64] = pa1.w;
        // Stage B: packed float4 e -> Bs[e>>6][(e&63)*4]
        {
            const int e0 = tid;        *(float4*)&Bs[buf][e0 >> 6][(e0 & 63) * 4] = pb0;
            const int e1 = tid + 256;  *(float4*)&Bs[buf][e1 >> 6][(e1 & 63) * 4] = pb1;
            const int e2 = tid + 512;  *(float4*)&Bs[buf][e2 >> 6][(e2 & 63) * 4] = pb2;
            const int e3 = tid + 768;  *(float4*)&Bs[buf][e3 >> 6][(e3 & 63) * 4] = pb3;
        }
        __syncthreads();

        if (kt + 1 < KT) {
            const int k0 = (kt + 1) * 16;
            pa0 = *(const float4*)(rp0 + k0 + q * 4);
            pa1 = *(const float4*)(rp1 + k0 + q * 4);
            const float4* wkt = (const float4*)(wtb + (size_t)(kt + 1) * 4096);
            pb0 = wkt[tid];
            pb1 = wkt[tid + 256];
            pb2 = wkt[tid + 512];
            pb3 = wkt[tid + 768];
        }

#pragma unroll 2
        for (int k = 0; k < 16; ++k) {
            float4 a0 = *(const float4*)&A[buf][k][ty * 16];
            float4 a1 = *(const float4*)&A[buf][k][ty * 16 + 4];
            float4 a2 = *(const float4*)&A[buf][k][ty * 16 + 8];
            float4 a3 = *(const float4*)&A[buf][k][ty * 16 + 12];
            float4 b0 = *(const float4*)&Bs[buf][k][tx * 4];
            float4 b1 = *(const float4*)&Bs[buf][k][128 + tx * 4];
            const float ar[16] = {a0.x, a0.y, a0.z, a0.w, a1.x, a1.y, a1.z, a1.w,
                                  a2.x, a2.y, a2.z, a2.w, a3.x, a3.y, a3.z, a3.w};
            const float br[8]  = {b0.x, b0.y, b0.z, b0.w, b1.x, b1.y, b1.z, b1.w};
#pragma unroll
            for (int i = 0; i < 16; ++i)
#pragma unroll
                for (int n = 0; n < 8; ++n) acc[i][n] += ar[i] * br[n];
        }
    }

    float4 bb0 = *(const float4*)(bias + d * NG4 + ct * 256 + tx * 4);
    float4 bb1 = *(const float4*)(bias + d * NG4 + ct * 256 + 128 + tx * 4);
#pragma unroll
    for (int i = 0; i < 16; ++i) {
        const int s = ty * 16 + i;
        float* zp = zin + (((size_t)(d * NB + b) * CHUNK + s)) * NG4 + ct * 256;
        float4 o0, o1;
        o0.x = acc[i][0] + bb0.x; o0.y = acc[i][1] + bb0.y;
        o0.z = acc[i][2] + bb0.z; o0.w = acc[i][3] + bb0.w;
        o1.x = acc[i][4] + bb1.x; o1.y = acc[i][5] + bb1.y;
        o1.z = acc[i][6] + bb1.z; o1.w = acc[i][7] + bb1.w;
        *(float4*)(zp + tx * 4) = o0;
        *(float4*)(zp + 128 + tx * 4) = o1;
    }
}

__global__ __launch_bounds__(256) void proj_l0(
    const float* __restrict__ wt, const float* __restrict__ bias,
    const float* __restrict__ xsrc, const int* __restrict__ inputs,
    float* __restrict__ zin, int c)
{ proj_body<128>(wt, bias, xsrc, inputs, zin, c); }

__global__ __launch_bounds__(256) void proj_l1(
    const float* __restrict__ wt, const float* __restrict__ bias,
    const float* __restrict__ xsrc, const int* __restrict__ inputs,
    float* __restrict__ zin, int c)
{ proj_body<256>(wt, bias, xsrc, inputs, zin, c); }

// ---------------------------------------------------------------------------
// Recurrent kernel (R15's exact ks8 WITH pin — best measured config, ~140us):
// 512 threads, wave (g,wv) = (row-half, k-quarter); w[4][32]/thread.
// ---------------------------------------------------------------------------
__global__ __launch_bounds__(512, 2) void lstm_rec_ks8(
    const float* __restrict__ Whh,     // [2][512][128]
    const float* __restrict__ zin,     // [2][B][CHUNK][512]
    float*       __restrict__ hout,    // [B][T][256]; slice [d*128, d*128+128)
    float*       __restrict__ state_h, // [2][B][128]
    float*       __restrict__ state_c, // [2][B][128]
    int c)
{
    __shared__ __align__(16) float h_lds[128];
    __shared__ __align__(16) float p_lds[4][512];   // [k-quarter][row]

    const int bid = blockIdx.x;  // d*128 + b
    const int d = bid >> 7, b = bid & 127;
    const int tid = threadIdx.x;
    const int wave = tid >> 6;
    const int g  = wave >> 2;    // row-half: rows [256g, 256g+256)
    const int wv = wave & 3;     // k-quarter: k in [32wv, 32wv+32)
    const int l  = tid & 63;

    // Weights: rows 256g + l + 64i (i=0..3), k in [32wv, 32wv+32).
    float w[4][32];
#pragma unroll
    for (int i = 0; i < 4; ++i) {
        const float* wr = Whh + ((size_t)(d * NG4 + 256 * g + l + 64 * i)) * NH + wv * 32;
#pragma unroll
        for (int kk = 0; kk < 32; kk += 4) {
            float4 t4 = *(const float4*)(wr + kk);
            w[i][kk] = t4.x; w[i][kk + 1] = t4.y; w[i][kk + 2] = t4.z; w[i][kk + 3] = t4.w;
        }
    }
    // Pin in VGPRs (opaque to optimizer).
#pragma unroll
    for (int i = 0; i < 4; ++i)
#pragma unroll
        for (int kk = 0; kk < 32; ++kk)
            asm volatile("" : "+v"(w[i][kk]));

    float c_reg = 0.0f;
    if (tid < 128) {
        float h0 = 0.0f;
        if (c != 0) {
            h0    = state_h[(d * NB + b) * NH + tid];
            c_reg = state_c[(d * NB + b) * NH + tid];
        }
        h_lds[tid] = h0;
    }
    __syncthreads();

    const float* zb = zin + ((size_t)(d * NB + b)) * CHUNK * NG4;

    for (int s = 0; s < CHUNK; ++s) {
        // gate lanes prefetch this step's zin early (in flight under FMA)
        float z0 = 0.f, z1 = 0.f, z2 = 0.f, z3 = 0.f;
        if (tid < 128) {
            const float* zr = zb + (size_t)s * NG4;
            z0 = zr[tid]; z1 = zr[128 + tid]; z2 = zr[256 + tid]; z3 = zr[384 + tid];
        }

        // FMA phase: read the wave's 32-float h segment (8 broadcast b128)
        float hv[32];
        const float* hp = h_lds + wv * 32;
#pragma unroll
        for (int kk = 0; kk < 32; kk += 4) {
            float4 t4 = *(const float4*)(hp + kk);
            hv[kk] = t4.x; hv[kk + 1] = t4.y; hv[kk + 2] = t4.z; hv[kk + 3] = t4.w;
        }
#pragma unroll
        for (int i = 0; i < 4; ++i) {
            float a = 0.0f;
#pragma unroll
            for (int kk = 0; kk < 32; ++kk) a += w[i][kk] * hv[kk];
            p_lds[wv][256 * g + l + 64 * i] = a;   // lanes consecutive: conflict-free
        }
        __syncthreads();

        if (tid < 128) {
            const float si = (p_lds[0][tid] + p_lds[1][tid]) + (p_lds[2][tid] + p_lds[3][tid]);
            const float sf = (p_lds[0][128 + tid] + p_lds[1][128 + tid]) + (p_lds[2][128 + tid] + p_lds[3][128 + tid]);
            const float sg = (p_lds[0][256 + tid] + p_lds[1][256 + tid]) + (p_lds[2][256 + tid] + p_lds[3][256 + tid]);
            const float so = (p_lds[0][384 + tid] + p_lds[1][384 + tid]) + (p_lds[2][384 + tid] + p_lds[3][384 + tid]);
            const float zi = z0 + si;
            const float zf = z1 + sf;
            const float zg = z2 + sg;
            const float zo = z3 + so;
            const float ig = sigf(zi), fg = sigf(zf), og = sigf(zo);
            c_reg = fg * c_reg + ig * tanhf(zg);
            const float hn = og * tanhf(c_reg);
            const int ttl = c * CHUNK + s;
            const int t   = d ? (NT - 1 - ttl) : ttl;
            h_lds[tid] = hn;
            hout[((size_t)(b * NT + t)) * 256 + d * NH + tid] = hn;
        }
        __syncthreads();
    }

    if (tid < 128) {
        state_h[(d * NB + b) * NH + tid] = h_lds[tid];
        state_c[(d * NB + b) * NH + tid] = c_reg;
    }
}

// ---------------------------------------------------------------------------
// Emissions: em[b][t][k] = b_out[k] + sum_c h2[b][t][c] * W_out[k][c]
// ---------------------------------------------------------------------------
__global__ __launch_bounds__(256) void emis_kernel(
    const float* __restrict__ h2,    // [B][T][256]
    const float* __restrict__ Wout,  // [32][256]
    const float* __restrict__ bout,  // [32]
    float*       __restrict__ em)    // [B][T][32]
{
    __shared__ float wt[256 * 32];               // transposed [c][k]
    __shared__ __align__(16) float hrow[8][256];

    const int tid = threadIdx.x;
    const int k = tid & 31;
    const int rl = tid >> 5;  // 0..7

    for (int e = tid; e < 8192; e += 256) {
        const int kk = e >> 8, cc = e & 255;
        wt[cc * 32 + kk] = Wout[e];
    }
    const float bk = bout[k];
    __syncthreads();

    const size_t base = (size_t)blockIdx.x * 64;
    for (int rr = 0; rr < 8; ++rr) {
        const size_t r0 = base + rr * 8;
        for (int e = tid; e < 512; e += 256) {
            ((float4*)&hrow[0][0])[e] = ((const float4*)(h2 + r0 * 256))[e];
        }
        __syncthreads();
        float acc = bk;
#pragma unroll 8
        for (int cc = 0; cc < 256; cc += 4) {
            float4 hv = *(const float4*)&hrow[rl][cc];
            acc += hv.x * wt[cc * 32 + k] + hv.y * wt[(cc + 1) * 32 + k] +
                   hv.z * wt[(cc + 2) * 32 + k] + hv.w * wt[(cc + 3) * 32 + k];
        }
        em[(r0 + rl) * NKT + k] = acc;
        __syncthreads();
    }
}

// ---------------------------------------------------------------------------
// Viterbi (R11's barrier-free single-wave scan — best of six variants, ~175us).
// ---------------------------------------------------------------------------
__global__ __launch_bounds__(64) void viterbi_nb(
    const float* __restrict__ em,      // [B][T][32]
    const float* __restrict__ start_t, // [32]
    const float* __restrict__ end_t,   // [32]
    const float* __restrict__ trans,   // [32][32]
    int*         __restrict__ out)     // [B][T]
{
    __shared__ float score[32];
    __shared__ float tr[1024];
    __shared__ float fsc[32];
    __shared__ unsigned char hist[(NT - 1) * 32];

    const int b = blockIdx.x;
    const int lane = threadIdx.x;
    const int j = lane & 31, h = lane >> 5;

    for (int e = lane; e < 1024; e += 64) tr[e] = trans[e];
    const float* emb_ = em + (size_t)b * NT * NKT;
    if (lane < 32) score[j] = start_t[j] + emb_[j];
    __syncthreads();  // once, before the scan

    float em_next = emb_[NKT + j];  // t = 1
    for (int t = 1; t < NT; ++t) {
        const float em_j = em_next;
        if (t + 1 < NT) em_next = emb_[(size_t)(t + 1) * NKT + j];
        float best = -1e30f;
        int bi = 0;
#pragma unroll
        for (int ii = 0; ii < 16; ++ii) {
            const int i = h * 16 + ii;
            const float v = (score[i] + tr[i * 32 + j]) + em_j;  // np add order
            if (v > best) { best = v; bi = i; }                  // strict >: first index wins
        }
        const float ob  = __shfl(best, lane ^ 32);
        const int   obi = __shfl(bi,   lane ^ 32);
        // no barrier: single-wave lockstep; DS ops in order
        if (h == 0) {
            float ns; int arg;
            if (ob > best) { ns = ob; arg = obi; }  // tie -> low half (smaller i)
            else           { ns = best; arg = bi; }
            score[j] = ns;
            hist[(t - 1) * 32 + j] = (unsigned char)arg;
        }
    }

    if (lane < 32) fsc[j] = score[j] + end_t[j];
    if (lane == 0) {
        float best = -1e30f; int bi = 0;
        for (int i = 0; i < 32; ++i) {
            const float v = fsc[i];
            if (v > best) { best = v; bi = i; }
        }
        int tag = bi;
        out[b * NT + (NT - 1)] = tag;
        for (int t = NT - 2; t >= 0; --t) {
            tag = hist[t * 32 + tag];
            out[b * NT + t] = tag;
        }
    }
}

// ---------------------------------------------------------------------------
extern "C" void kernel_launch(void* const* d_in, const int* in_sizes, int n_in,
                              void* d_out, int out_size, void* d_ws, size_t ws_size,
                              hipStream_t stream) {
    const int*   inputs  = (const int*)d_in[0];
    // d_in[1] = tags (unused by forward/decode)
    const float* emb     = (const float*)d_in[2];
    const float* w_ih_l0 = (const float*)d_in[3];
    const float* w_hh_l0 = (const float*)d_in[4];
    const float* b_l0    = (const float*)d_in[5];
    const float* w_ih_l1 = (const float*)d_in[6];
    const float* w_hh_l1 = (const float*)d_in[7];
    const float* b_l1    = (const float*)d_in[8];
    const float* W_out   = (const float*)d_in[9];
    const float* b_out   = (const float*)d_in[10];
    const float* start_t = (const float*)d_in[11];
    const float* end_t   = (const float*)d_in[12];
    const float* trans   = (const float*)d_in[13];
    int* out = (int*)d_out;

    float* ws  = (float*)d_ws;
    float* zin = ws;                                        // 2*B*128*512
    float* h1  = zin + (size_t)2 * NB * CHUNK * NG4;        // B*T*256
    float* h2  = h1 + (size_t)NB * NT * 256;                // B*T*256
    float* sth = h2 + (size_t)NB * NT * 256;                // 2*B*128
    float* stc = sth + (size_t)2 * NB * NH;                 // 2*B*128
    float* em  = stc + (size_t)2 * NB * NH;                 // B*T*32
    float* wt0 = em + (size_t)NB * NT * NKT;                // 2*512*128
    float* wt1 = wt0 + (size_t)2 * 512 * 128;               // 2*512*256

    // Pre-pack weights into k-major staging layout (coalesced proj B-loads).
    prep_w<<<512, 256, 0, stream>>>(w_ih_l0, wt0, 128);
    prep_w<<<1024, 256, 0, stream>>>(w_ih_l1, wt1, 256);

    // Layer 0: chunked input-projection GEMM + recurrence
    for (int c = 0; c < NCH; ++c) {
        proj_l0<<<512, 256, 0, stream>>>(wt0, b_l0, emb, inputs, zin, c);
        lstm_rec_ks8<<<256, 512, 0, stream>>>(w_hh_l0, zin, h1, sth, stc, c);
    }
    // Layer 1
    for (int c = 0; c < NCH; ++c) {
        proj_l1<<<512, 256, 0, stream>>>(wt1, b_l1, h1, nullptr, zin, c);
        lstm_rec_ks8<<<256, 512, 0, stream>>>(w_hh_l1, zin, h2, sth, stc, c);
    }
    // Emissions + Viterbi decode
    emis_kernel<<<(NB * NT) / 64, 256, 0, stream>>>(h2, W_out, b_out, em);
    viterbi_nb<<<NB, 64, 0, stream>>>(em, start_t, end_t, trans, out);
}